// Round 7
// baseline (138.625 us; speedup 1.0000x reference)
//
#include <hip/hip_runtime.h>
#include <math.h>

#define FH 384
#define FW 384
#define DH 96
#define DW 96
#define NIMG 6   // 0,1: pred b0,b1; 2,3: I[:,0] b0,b1; 4,5: I[:,1] b0,b1
#define PLANE (DH * DW)
#define NPIX (2 * PLANE)

// Keys cubic kernel, a = -0.5 (matches jax.image "cubic")
__device__ __forceinline__ float keysc(float x) {
    if (x < 1.f) return ((1.5f * x - 2.5f) * x) * x + 1.f;
    if (x < 2.f) return ((-0.5f * x + 2.5f) * x - 4.f) * x + 2.f;
    return 0.f;
}

// reflect-101 (jnp.pad mode='reflect'), valid for i in [-(n-1), 2n-2]
__device__ __forceinline__ int refl(int i, int n) {
    if (i < 0) i = -i;
    if (i >= n) i = 2 * (n - 1) - i;
    return i;
}

__device__ __forceinline__ int clampi(int i) { return min(max(i, 0), 95); }

// soft census normalize — EXACT expression (keep!)
__device__ __forceinline__ float softsign(float t) {
    return t / sqrtf(0.81f + t * t);
}

// ---------------- K2: gray + census + downH + downW, fully fused -----------
// block = one (img, yo) row, 384 threads; writes CD census planes directly
__global__ __launch_bounds__(384) void k_census_down(const float* __restrict__ pred,
                                                     const float* __restrict__ I,
                                                     float* __restrict__ CD) {
    __shared__ float g[18][FW];     // gray rows rbase-1 .. rbase+16 (0 outside)
    __shared__ float ct[9][FW];     // census channels for this yo row

    int bid = blockIdx.x;           // img*96 + yo
    int img = bid / DH;
    int yo  = bid % DH;
    int tid = threadIdx.x;          // x in [0,384)

    const float* src;
    if (img < 2) {
        src = pred + img * 3 * FH * FW;
    } else {
        int j = (img - 2) >> 1, b = (img - 2) & 1;
        src = I + ((b * 2 + j) * 3) * FH * FW;
    }

    int rbase = 4 * yo - 6;
    // ---- stage 18 gray rows (grayscale computed inline; invalid rows = 0)
    for (int u = 0; u < 18; ++u) {
        int r = rbase - 1 + u;
        float v = 0.f;
        if (r >= 0 && r < FH) {
            const float* s = src + r * FW + tid;
            v = (0.299f * s[0] + 0.587f * s[FH * FW] + 0.114f * s[2 * FH * FW]) * 255.0f;
        }
        g[u][tid] = v;
    }
    __syncthreads();

    // ---- census + H-downsample from LDS (sliding 3-row window)
    {
        bool xl = (tid > 0), xr = (tid < FW - 1);
        float a0, a1, a2, b0, b1, b2, c0, c1, c2;
        a1 = g[0][tid]; a0 = xl ? g[0][tid - 1] : 0.f; a2 = xr ? g[0][tid + 1] : 0.f;
        b1 = g[1][tid]; b0 = xl ? g[1][tid - 1] : 0.f; b2 = xr ? g[1][tid + 1] : 0.f;

        float acc0 = 0.f, acc1 = 0.f, acc2 = 0.f, acc3 = 0.f, acc5 = 0.f,
              acc6 = 0.f, acc7 = 0.f, acc8 = 0.f, z = 0.f;
#pragma unroll
        for (int t = 0; t < 16; ++t) {
            int u = t + 2;
            c1 = g[u][tid]; c0 = xl ? g[u][tid - 1] : 0.f; c2 = xr ? g[u][tid + 1] : 0.f;
            int r = rbase + t;
            if (r >= 0 && r < FH) {          // uniform branch per block
                float w = keysc(fabsf((float)t - 7.5f) * 0.25f);
                z += w;
                float gc = b1;
                acc0 += w * softsign(a0 - gc);
                acc1 += w * softsign(a1 - gc);
                acc2 += w * softsign(a2 - gc);
                acc3 += w * softsign(b0 - gc);
                acc5 += w * softsign(b2 - gc);
                acc6 += w * softsign(c0 - gc);
                acc7 += w * softsign(c1 - gc);
                acc8 += w * softsign(c2 - gc);
            }
            a0 = b0; a1 = b1; a2 = b2;
            b0 = c0; b1 = c1; b2 = c2;
        }
        float inv = 1.f / z;
        ct[0][tid] = acc0 * inv;
        ct[1][tid] = acc1 * inv;
        ct[2][tid] = acc2 * inv;
        ct[3][tid] = acc3 * inv;
        ct[4][tid] = 0.f;                    // center channel exactly 0
        ct[5][tid] = acc5 * inv;
        ct[6][tid] = acc6 * inv;
        ct[7][tid] = acc7 * inv;
        ct[8][tid] = acc8 * inv;
    }
    __syncthreads();

    // ---- W-downsample 9 channels -> CD
    for (int idx = tid; idx < 9 * DW; idx += 384) {
        int ch = idx / DW;
        int xo = idx % DW;
        float acc = 0.f, z = 0.f;
#pragma unroll
        for (int t = 0; t < 16; ++t) {
            int i = 4 * xo - 6 + t;
            if (i < 0 || i >= FW) continue;
            float w = keysc(fabsf((float)t - 7.5f) * 0.25f);
            z += w;
            acc += w * ct[ch][i];
        }
        CD[(img * 9 + ch) * PLANE + yo * DW + xo] = acc / z;
    }
}

// ---------------- K3: generic downsample along W (raw rows only) -----------
__global__ void k_downW(const float* __restrict__ src, float* __restrict__ dst, int nrows) {
    int idx = blockIdx.x * 256 + threadIdx.x;
    int total = nrows * DW;
    if (idx >= total) return;
    int xo = idx % DW;
    int row = idx / DW;
    const float* s = src + row * FW;
    float acc = 0.f, z = 0.f;
#pragma unroll
    for (int t = 0; t < 16; ++t) {
        int i = 4 * xo - 6 + t;
        if (i < 0 || i >= FW) continue;
        float w = keysc(fabsf((float)t - 7.5f) * 0.25f);
        z += w;
        acc += w * s[i];
    }
    dst[idx] = acc / z;
}

// ---------------- K4: raw channels downsample along H ----------------------
__global__ void k_raw_downH(const float* __restrict__ pred, const float* __restrict__ I,
                            float* __restrict__ RH) {
    int idx = blockIdx.x * 256 + threadIdx.x;
    const int total = NIMG * 3 * DH * FW;
    if (idx >= total) return;
    int x  = idx % FW;
    int t1 = idx / FW;
    int yo = t1 % DH;
    int t2 = t1 / DH;
    int c  = t2 % 3;
    int img = t2 / 3;
    const float* src;
    if (img < 2) {
        src = pred + (img * 3 + c) * FH * FW;
    } else {
        int j = (img - 2) >> 1, b = (img - 2) & 1;
        src = I + (((b * 2 + j) * 3) + c) * FH * FW;
    }
    float acc = 0.f, z = 0.f;
#pragma unroll
    for (int t = 0; t < 16; ++t) {
        int r = 4 * yo - 6 + t;
        if (r < 0 || r >= FH) continue;
        float w = keysc(fabsf((float)t - 7.5f) * 0.25f);
        z += w;
        acc += w * src[r * FW + x];
    }
    RH[idx] = acc / z;
}

// ---------------- K5: n2 per (neighbor image, position) --------------------
__global__ void k_n2(const float* __restrict__ CD, float* __restrict__ N2) {
    int idx = blockIdx.x * 256 + threadIdx.x;
    if (idx >= 4 * PLANE) return;
    int img4 = idx / PLANE;
    int pos  = idx % PLANE;
    int y = pos / DW, x = pos % DW;
    int ry[3], rx[3];
#pragma unroll
    for (int kk = 0; kk < 3; ++kk) {
        ry[kk] = refl(y + kk - 1, DH);
        rx[kk] = refl(x + kk - 1, DW);
    }
    const float* C = CD + (2 + img4) * 9 * PLANE;
    float s = 0.f;
#pragma unroll
    for (int c = 0; c < 9; ++c)
#pragma unroll
        for (int ky = 0; ky < 3; ++ky)
#pragma unroll
            for (int kx = 0; kx < 3; ++kx) {
                float v = C[c * PLANE + ry[ky] * DW + rx[kx]];
                s += v * v;
            }
    N2[idx] = s;
}

// ---------------- K6: matching, j-split, register center patch -------------
// block = 32 px x 8 groups, one j; grid = 2j * (2b * 96y * 3xt) = 1152
__global__ __launch_bounds__(256, 1) void k_match(const float* __restrict__ CD,
                                                  const float* __restrict__ N2,
                                                  float* __restrict__ bestd,
                                                  int* __restrict__ bestn) {
    __shared__ float nb[9][9][40];      // [c][row y-4+u][col x0-4+v] for this j
    __shared__ float ct[9][3][34];      // [c][row y-1+u][col x0-1+v]
    __shared__ float sbd[256];
    __shared__ int   sbn[256];

    int bid = blockIdx.x;               // j*576 + b*288 + y*3 + xt
    int j   = bid / 576;
    int sub = bid % 576;
    int b   = sub / 288;
    int rem = sub % 288;
    int y   = rem / 3;
    int x0  = (rem % 3) * 32;

    int px = threadIdx.x & 31;
    int g  = threadIdx.x >> 5;          // candidate group 0..7
    int x  = x0 + px;

    // ---- stage neighbor window for this j (clamped; unused slots never read)
    for (int idx = threadIdx.x; idx < 9 * 9 * 40; idx += 256) {
        int c  = idx / 360;
        int r2 = idx % 360;
        int u  = r2 / 40;
        int v  = r2 % 40;
        int gy = clampi(y - 4 + u);
        int gx = clampi(x0 - 4 + v);
        nb[c][u][v] = CD[((2 + 2 * j + b) * 9 + c) * PLANE + gy * DW + gx];
    }
    // ---- stage center window
    for (int idx = threadIdx.x; idx < 9 * 3 * 34; idx += 256) {
        int c  = idx / 102;
        int r1 = idx % 102;
        int u  = r1 / 34;
        int v  = r1 % 34;
        int gy = clampi(y - 1 + u);
        int gx = clampi(x0 - 1 + v);
        ct[c][u][v] = CD[(b * 9 + c) * PLANE + gy * DW + gx];
    }
    __syncthreads();

    // center patch -> registers; asm barrier forces true materialization
    int cy_s[3], cx_s[3];
#pragma unroll
    for (int kk = 0; kk < 3; ++kk) {
        cy_s[kk] = refl(y + kk - 1, DH) - (y - 1);
        cx_s[kk] = refl(x + kk - 1, DW) - (x0 - 1);
    }
    float p[81];
#pragma unroll
    for (int c = 0; c < 9; ++c)
#pragma unroll
        for (int ky = 0; ky < 3; ++ky)
#pragma unroll
            for (int kx = 0; kx < 3; ++kx)
                p[c * 9 + ky * 3 + kx] = ct[c][cy_s[ky]][cx_s[kx]];
#pragma unroll
    for (int f = 0; f < 81; ++f) asm volatile("" : "+v"(p[f]));

    float best = INFINITY;
    int bn = 1 << 30;
#pragma unroll
    for (int k = 0; k < 7; ++k) {
        int rr = 8 * k + g;
        if (rr < 49) {
            int dy = rr / 7 - 3, dx = rr % 7 - 3;
            int yy = refl(y + dy, DH), xx = refl(x + dx, DW);   // first reflect
            int ry_s[3], rx_s[3];
#pragma unroll
            for (int kk = 0; kk < 3; ++kk) {                    // second reflect
                ry_s[kk] = refl(yy + kk - 1, DH) - (y - 4);
                rx_s[kk] = refl(xx + kk - 1, DW) - (x0 - 4);
            }
            float dot = 0.f;
#pragma unroll
            for (int c = 0; c < 9; ++c)
#pragma unroll
                for (int ky = 0; ky < 3; ++ky)
#pragma unroll
                    for (int kx = 0; kx < 3; ++kx)
                        dot += p[c * 9 + ky * 3 + kx] * nb[c][ry_s[ky]][rx_s[kx]];
            float dis = N2[(2 * j + b) * PLANE + yy * DW + xx] - 2.f * dot;
            if (dis < best) { best = dis; bn = j * 49 + rr; }   // rr ascending
        }
    }
    sbd[threadIdx.x] = best;
    sbn[threadIdx.x] = bn;
    __syncthreads();

    // per-pixel lex-min across the 8 groups -> global (best, n) for this j
    if (g == 0) {
        float d0 = sbd[px];
        int   n0 = sbn[px];
#pragma unroll
        for (int gg = 1; gg < 8; ++gg) {
            float d = sbd[gg * 32 + px];
            int   n = sbn[gg * 32 + px];
            if (d < d0 || (d == d0 && n < n0)) { d0 = d; n0 = n; }
        }
        int pid = b * PLANE + y * DW + x;
        bestd[j * NPIX + pid] = d0;
        bestn[j * NPIX + pid] = n0;
    }
}

// ---------------- K7: combine j-halves + loss gather -----------------------
__global__ __launch_bounds__(256) void k_combine(const float* __restrict__ bestd,
                                                 const int* __restrict__ bestn,
                                                 const float* __restrict__ RD,
                                                 float* __restrict__ partial) {
    int pid = blockIdx.x * 256 + threadIdx.x;   // 0..18431
    int b   = pid / PLANE;
    int pos = pid % PLANE;
    int y = pos / DW, x = pos % DW;

    float d0 = bestd[pid];
    int   n0 = bestn[pid];
    float d1 = bestd[NPIX + pid];
    int   n1 = bestn[NPIX + pid];
    if (d1 < d0 || (d1 == d0 && n1 < n0)) { d0 = d1; n0 = n1; }

    int j = n0 / 49, rr = n0 % 49;
    int dy = rr / 7 - 3, dx = rr % 7 - 3;
    int yy = refl(y + dy, DH), xx = refl(x + dx, DW);
    int ry0[3], rx0[3], ry[3], rx[3];
#pragma unroll
    for (int kk = 0; kk < 3; ++kk) {
        ry0[kk] = refl(y + kk - 1, DH);
        rx0[kk] = refl(x + kk - 1, DW);
        ry[kk]  = refl(yy + kk - 1, DH);
        rx[kk]  = refl(xx + kk - 1, DW);
    }
    const float* RDp = RD + b * 3 * PLANE;
    const float* RDn = RD + (2 + 2 * j + b) * 3 * PLANE;
    float loss = 0.f;
#pragma unroll
    for (int c = 0; c < 3; ++c)
#pragma unroll
        for (int ky = 0; ky < 3; ++ky)
#pragma unroll
            for (int kx = 0; kx < 3; ++kx) {
                float a = RDp[c * PLANE + ry0[ky] * DW + rx0[kx]];
                float m = RDn[c * PLANE + ry[ky] * DW + rx[kx]];
                float d = a - m;
                loss += d * d;
            }

    __shared__ float red[256];
    red[threadIdx.x] = loss;
    __syncthreads();
#pragma unroll
    for (int s = 128; s > 0; s >>= 1) {
        if (threadIdx.x < s) red[threadIdx.x] += red[threadIdx.x + s];
        __syncthreads();
    }
    if (threadIdx.x == 0) partial[blockIdx.x] = red[0];
}

// ---------------- K8: final reduction --------------------------------------
#define NPART 72
__global__ void k_final(const float* __restrict__ partial, float* __restrict__ out) {
    __shared__ float red[128];
    float v = (threadIdx.x < NPART) ? partial[threadIdx.x] : 0.f;
    red[threadIdx.x] = v;
    __syncthreads();
#pragma unroll
    for (int s = 64; s > 0; s >>= 1) {
        if (threadIdx.x < s) red[threadIdx.x] += red[threadIdx.x + s];
        __syncthreads();
    }
    // mean over [b=2, hw=9216, 27] with the 0.5 factor
    if (threadIdx.x == 0) out[0] = red[0] * (0.5f / 497664.0f);
}

extern "C" void kernel_launch(void* const* d_in, const int* in_sizes, int n_in,
                              void* d_out, int out_size, void* d_ws, size_t ws_size,
                              hipStream_t stream) {
    const float* pred = (const float*)d_in[0];   // [2,3,384,384]
    const float* I    = (const float*)d_in[1];   // [2,2,3,384,384]
    float* out = (float*)d_out;
    float* ws  = (float*)d_ws;

    // workspace layout (floats):
    //   CD   [0, 497664)                 6*9*96*96
    //   RD   [497664, 663552)            6*3*96*96
    //   S = 663552:
    //     RH    [S, S+663552)            6*3*96*384 (dead after downW)
    //   reused after downW:
    //     N2    [S, S+36864)             4*9216
    //     bestd [S+36864, S+73728)       2*18432
    //     bestn [S+73728, S+110592)      2*18432 (int)
    //     part  [S+110592, S+110664)     72
    float* CD   = ws;
    float* RD   = CD + 497664;
    float* S    = RD + 165888;
    float* RH   = S;
    float* N2   = S;
    float* bestd = S + 36864;
    int*   bestn = (int*)(S + 73728);
    float* part  = S + 110592;

    k_census_down<<<NIMG * DH, 384, 0, stream>>>(pred, I, CD);
    k_raw_downH<<<(NIMG * 3 * DH * FW + 255) / 256, 256, 0, stream>>>(pred, I, RH);
    k_downW<<<((NIMG * 3 * DH) * DW + 255) / 256, 256, 0, stream>>>(RH, RD, NIMG * 3 * DH);
    k_n2<<<(4 * PLANE + 255) / 256, 256, 0, stream>>>(CD, N2);
    k_match<<<1152, 256, 0, stream>>>(CD, N2, bestd, bestn);
    k_combine<<<NPIX / 256, 256, 0, stream>>>(bestd, bestn, RD, part);
    k_final<<<1, 128, 0, stream>>>(part, out);
}